// Round 9
// baseline (209.600 us; speedup 1.0000x reference)
//
#include <hip/hip_runtime.h>

#define T_SEQ 2048
#define DIM   768
#define NH    12
#define HD    64

typedef __attribute__((ext_vector_type(8))) short short8;
typedef __attribute__((ext_vector_type(4))) float floatx4;
typedef __attribute__((ext_vector_type(4))) unsigned short ushort4v;

#define MFMA16(a,b,c) __builtin_amdgcn_mfma_f32_16x16x32_bf16((a),(b),(c),0,0,0)

static __device__ __forceinline__ unsigned short f2bf(float f){
  union { float f; unsigned u; } v; v.f = f;
  unsigned r = v.u + 0x7fffu + ((v.u >> 16) & 1u);
  return (unsigned short)(r >> 16);
}

// ---------------- fp32 -> bf16 conversion of x, Wq|Wk|Wv, Wp ----------------
__global__ void convert_kernel(const float* __restrict__ x,
                               const float* __restrict__ wq,
                               const float* __restrict__ wk,
                               const float* __restrict__ wv,
                               const float* __restrict__ wp,
                               unsigned short* __restrict__ xb,
                               unsigned short* __restrict__ wqkvb,
                               unsigned short* __restrict__ wpb){
  const int stride = gridDim.x * blockDim.x;
  const int i0 = blockIdx.x * blockDim.x + threadIdx.x;
  const int XN = T_SEQ * DIM;
  const int WN = DIM * DIM;
  for (int i = i0; i < XN; i += stride) xb[i] = f2bf(x[i]);
  for (int i = i0; i < WN; i += stride) {
    wqkvb[i]        = f2bf(wq[i]);
    wqkvb[WN + i]   = f2bf(wk[i]);
    wqkvb[2*WN + i] = f2bf(wv[i]);
    wpb[i]          = f2bf(wp[i]);
  }
}

// ---------------- QKV projection + lerp + rmsnorm + rope --------------------
// One wave per block computes a 64x64 output tile (4x4 MFMA accumulators).
// grid (32, 36): cb/12 = {q,k,v}, cb%12 = head.
__global__ __launch_bounds__(64) void qkv_kernel(
    const unsigned short* __restrict__ xb,
    const unsigned short* __restrict__ wqkvb,
    const float* __restrict__ vi,
    const float* __restrict__ lambp,
    unsigned short* __restrict__ qb,   // [NH][T][HD]
    unsigned short* __restrict__ kb,   // [NH][T][HD]
    unsigned short* __restrict__ vT){  // [NH][HD][T]
  const int l  = threadIdx.x;
  const int lr = l & 15, lq = l >> 4;
  const int rb = blockIdx.x, cb = blockIdx.y;
  const int mat = cb / NH, head = cb % NH;
  const int row0 = rb*64;

  floatx4 acc[4][4];
  #pragma unroll
  for (int i=0;i<4;i++)
    #pragma unroll
    for (int j=0;j<4;j++) acc[i][j] = (floatx4){0.f,0.f,0.f,0.f};

  const unsigned short* Ab = xb + (size_t)(row0 + lr)*DIM + lq*8;
  const unsigned short* Bb = wqkvb + (size_t)mat*DIM*DIM
                           + (size_t)(head*HD + lr)*DIM + lq*8;

  short8 a[4], b[4];
  #pragma unroll
  for (int rt=0;rt<4;rt++) a[rt] = *(const short8*)(Ab + (size_t)rt*16*DIM);
  #pragma unroll
  for (int ct=0;ct<4;ct++) b[ct] = *(const short8*)(Bb + (size_t)ct*16*DIM);

  for (int k0 = 0; k0 < DIM; k0 += 32){
    const int kn = (k0 + 32 < DIM) ? k0 + 32 : 0;   // wrap tail: unconditional loads
    short8 an[4], bn[4];
    #pragma unroll
    for (int rt=0;rt<4;rt++) an[rt] = *(const short8*)(Ab + (size_t)rt*16*DIM + kn);
    #pragma unroll
    for (int ct=0;ct<4;ct++) bn[ct] = *(const short8*)(Bb + (size_t)ct*16*DIM + kn);
    #pragma unroll
    for (int rt=0;rt<4;rt++)
      #pragma unroll
      for (int ct=0;ct<4;ct++)
        acc[rt][ct] = MFMA16(a[rt], b[ct], acc[rt][ct]);
    #pragma unroll
    for (int rt=0;rt<4;rt++) a[rt] = an[rt];
    #pragma unroll
    for (int ct=0;ct<4;ct++) b[ct] = bn[ct];
  }

  if (mat == 2){
    const float lamb = *lambp;
    #pragma unroll
    for (int rt=0;rt<4;rt++){
      const int tb = row0 + rt*16 + lq*4;
      #pragma unroll
      for (int ct=0;ct<4;ct++){
        const int d = ct*16 + lr;
        ushort4v pk;
        #pragma unroll
        for (int r=0;r<4;r++){
          float vv = (1.0f - lamb)*acc[rt][ct][r]
                   + lamb * vi[(size_t)(tb + r)*DIM + head*HD + d];
          pk[r] = f2bf(vv);
        }
        *(ushort4v*)(vT + (size_t)(head*HD + d)*T_SEQ + tb) = pk;
      }
    }
  } else {
    unsigned short* dst = (mat==0 ? qb : kb) + (size_t)head*T_SEQ*HD;
    #pragma unroll
    for (int rt=0;rt<4;rt++){
      float ss[4];
      #pragma unroll
      for (int r=0;r<4;r++)
        ss[r] = acc[rt][0][r]*acc[rt][0][r] + acc[rt][1][r]*acc[rt][1][r]
              + acc[rt][2][r]*acc[rt][2][r] + acc[rt][3][r]*acc[rt][3][r];
      #pragma unroll
      for (int mm=1; mm<16; mm<<=1){
        #pragma unroll
        for (int r=0;r<4;r++) ss[r] += __shfl_xor(ss[r], mm);
      }
      float scl[4];
      #pragma unroll
      for (int r=0;r<4;r++)
        scl[r] = rsqrtf(ss[r]*(1.0f/64.0f) + 1.1920929e-7f);

      #pragma unroll
      for (int ct=0;ct<2;ct++){
        const int i = ct*16 + lr;               // rope pair index 0..31
        const float inv = __expf(-(float)i * (9.210340371976184f/32.0f));
        #pragma unroll
        for (int r=0;r<4;r++){
          const int t = row0 + rt*16 + lq*4 + r;
          const float f = (float)t * inv;
          const float c = cosf(f), s = sinf(f);
          const float x1 = acc[rt][ct][r]*scl[r], x2 = acc[rt][ct+2][r]*scl[r];
          dst[(size_t)t*HD + i]      = f2bf(x1*c + x2*s);
          dst[(size_t)t*HD + i + 32] = f2bf(x2*c - x1*s);
        }
      }
    }
  }
}

// ---------------- causal flash attention (MFMA, fixed-max, 8-way split-K) ---
// Scores bounded: rmsnorm rows have norm 8 => s = q.k/8 in [-8,8]; fixed max 8.
// grid (128, 12): block bx handles q-tile qt = 127-bx (heavy first).
// 8 waves split the key range (kt = w, w+8, ...); partial (O,l) summed via LDS.
// LDS overlay: P-transpose slabs (20.5KB) and fp32 partial-O (32KB) share the
// same region -- a barrier separates the two uses. 33.3KB -> 4 blocks/CU.
__global__ __launch_bounds__(512) void attn_kernel(
    const unsigned short* __restrict__ qb,
    const unsigned short* __restrict__ kb,
    const unsigned short* __restrict__ vT,
    unsigned short* __restrict__ yb){   // [T][DIM] token-major
  __shared__ __align__(16) char smem[33280];
  // while looping: slab(dbuf,w) = smem + (dbuf*8+w)*1280  (16 rows x 40 shorts)
  // after barrier: Oshf = (float*)smem, [w][64][16]; lsh = smem+32768, [w][16]
  float* Oshf = (float*)smem;
  float* lsh  = (float*)(smem + 32768);

  const int w  = threadIdx.x >> 6;
  const int l  = threadIdx.x & 63;
  const int lr = l & 15, lq = l >> 4;
  const int head = blockIdx.y;
  const int qt = 127 - (int)blockIdx.x;
  const int q0 = qt*16;

  const unsigned short* Q = qb + (size_t)head*T_SEQ*HD;
  const unsigned short* K = kb + (size_t)head*T_SEQ*HD;
  const unsigned short* V = vT + (size_t)head*HD*T_SEQ;

  const short8 qf0 = *(const short8*)(Q + (size_t)(q0+lr)*HD + lq*8);
  const short8 qf1 = *(const short8*)(Q + (size_t)(q0+lr)*HD + 32 + lq*8);

  floatx4 O[4];
  #pragma unroll
  for (int nt=0; nt<4; nt++) O[nt] = (floatx4){0.f,0.f,0.f,0.f};
  float lsum[4] = {0.f,0.f,0.f,0.f};

  const int ntile = (q0 + 15)/32 + 1;
  int kt = w;
  short8 kf0, kf1, kf2, kf3;
  if (kt < ntile){
    const unsigned short* kp = K + (size_t)(kt*32 + lr)*HD + lq*8;
    kf0 = *(const short8*)kp;            kf1 = *(const short8*)(kp + 32);
    kf2 = *(const short8*)(kp + 16*HD);  kf3 = *(const short8*)(kp + 16*HD + 32);
  }
  int dbuf = 0;
  for (; kt < ntile; kt += 8, dbuf ^= 1){
    const int kbase = kt*32;
    short8 vf[4];
    #pragma unroll
    for (int nt=0; nt<4; nt++)
      vf[nt] = *(const short8*)(V + (size_t)(nt*16 + lr)*T_SEQ + kbase + lq*8);

    floatx4 S0 = (floatx4){0.f,0.f,0.f,0.f};
    floatx4 S1 = (floatx4){0.f,0.f,0.f,0.f};
    S0 = MFMA16(qf0, kf0, S0);
    S0 = MFMA16(qf1, kf1, S0);
    S1 = MFMA16(qf0, kf2, S1);
    S1 = MFMA16(qf1, kf3, S1);

    const int ktn = kt + 8;
    if (ktn < ntile){
      const unsigned short* kp = K + (size_t)(ktn*32 + lr)*HD + lq*8;
      kf0 = *(const short8*)kp;            kf1 = *(const short8*)(kp + 32);
      kf2 = *(const short8*)(kp + 16*HD);  kf3 = *(const short8*)(kp + 16*HD + 32);
    }

    // p = exp(s - 8), s = S*0.125  =>  exp2(S*0.125*log2e - 8*log2e)
    float p0[4], p1[4];
    const int qr = q0 + lq*4;
    #pragma unroll
    for (int r=0; r<4; r++){
      float e0 = __builtin_amdgcn_exp2f(S0[r]*0.18033688011112043f - 11.541560327111707f);
      float e1 = __builtin_amdgcn_exp2f(S1[r]*0.18033688011112043f - 11.541560327111707f);
      p0[r] = (kbase + lr      > qr + r) ? 0.f : e0;
      p1[r] = (kbase + 16 + lr > qr + r) ? 0.f : e1;
      lsum[r] += p0[r] + p1[r];
    }

    // P: C-layout -> A-layout through per-wave LDS slab (double buffered)
    unsigned short* pl = (unsigned short*)(smem + (dbuf*8 + w)*1280);
    #pragma unroll
    for (int r=0; r<4; r++){
      const int row = lq*4 + r;
      pl[row*40 + lr]      = f2bf(p0[r]);
      pl[row*40 + 16 + lr] = f2bf(p1[r]);
    }
    __asm__ volatile("s_waitcnt lgkmcnt(0)" ::: "memory");
    const short8 pf = *(const short8*)(pl + lr*40 + lq*8);

    #pragma unroll
    for (int nt=0; nt<4; nt++) O[nt] = MFMA16(pf, vf[nt], O[nt]);
  }

  // per-wave l reduction (rows lq*4+r live across the 16 lr lanes)
  #pragma unroll
  for (int mm=1; mm<16; mm<<=1){
    #pragma unroll
    for (int r=0; r<4; r++) lsum[r] += __shfl_xor(lsum[r], mm);
  }

  __syncthreads();   // all waves done with plds before Oshf overlay is written

  if (lr == 0){
    #pragma unroll
    for (int r=0; r<4; r++) lsh[w*16 + lq*4 + r] = lsum[r];
  }
  #pragma unroll
  for (int nt=0; nt<4; nt++)
    *(floatx4*)&Oshf[((size_t)w*64 + l)*16 + nt*4] = O[nt];
  __syncthreads();

  if (w == 0){
    float L[4] = {0.f,0.f,0.f,0.f};
    float Of[4][4];
    #pragma unroll
    for (int nt=0; nt<4; nt++)
      #pragma unroll
      for (int r=0; r<4; r++) Of[nt][r] = 0.f;
    #pragma unroll
    for (int ww=0; ww<8; ww++){
      #pragma unroll
      for (int r=0; r<4; r++) L[r] += lsh[ww*16 + lq*4 + r];
      #pragma unroll
      for (int nt=0; nt<4; nt++){
        floatx4 t = *(const floatx4*)&Oshf[((size_t)ww*64 + l)*16 + nt*4];
        #pragma unroll
        for (int r=0; r<4; r++) Of[nt][r] += t[r];
      }
    }
    #pragma unroll
    for (int nt=0; nt<4; nt++){
      #pragma unroll
      for (int r=0; r<4; r++){
        yb[(size_t)(q0 + lq*4 + r)*DIM + head*HD + nt*16 + lr]
            = f2bf(Of[nt][r] / L[r]);
      }
    }
  }
}

// ---------------- output projection (fp32 out, 64x64 per wave) --------------
// grid (32, 12), one wave per block.
__global__ __launch_bounds__(64) void proj_kernel(
    const unsigned short* __restrict__ yb,
    const unsigned short* __restrict__ wpb,
    float* __restrict__ out){
  const int l  = threadIdx.x;
  const int lr = l & 15, lq = l >> 4;
  const int rb = blockIdx.x, cb = blockIdx.y;
  const int row0 = rb*64, col0 = cb*64;

  floatx4 acc[4][4];
  #pragma unroll
  for (int i=0;i<4;i++)
    #pragma unroll
    for (int j=0;j<4;j++) acc[i][j] = (floatx4){0.f,0.f,0.f,0.f};

  const unsigned short* Ab = yb + (size_t)(row0 + lr)*DIM + lq*8;
  const unsigned short* Bb = wpb + (size_t)(col0 + lr)*DIM + lq*8;

  short8 a[4], b[4];
  #pragma unroll
  for (int rt=0;rt<4;rt++) a[rt] = *(const short8*)(Ab + (size_t)rt*16*DIM);
  #pragma unroll
  for (int ct=0;ct<4;ct++) b[ct] = *(const short8*)(Bb + (size_t)ct*16*DIM);

  for (int k0 = 0; k0 < DIM; k0 += 32){
    const int kn = (k0 + 32 < DIM) ? k0 + 32 : 0;
    short8 an[4], bn[4];
    #pragma unroll
    for (int rt=0;rt<4;rt++) an[rt] = *(const short8*)(Ab + (size_t)rt*16*DIM + kn);
    #pragma unroll
    for (int ct=0;ct<4;ct++) bn[ct] = *(const short8*)(Bb + (size_t)ct*16*DIM + kn);
    #pragma unroll
    for (int rt=0;rt<4;rt++)
      #pragma unroll
      for (int ct=0;ct<4;ct++)
        acc[rt][ct] = MFMA16(a[rt], b[ct], acc[rt][ct]);
    #pragma unroll
    for (int rt=0;rt<4;rt++) a[rt] = an[rt];
    #pragma unroll
    for (int ct=0;ct<4;ct++) b[ct] = bn[ct];
  }

  #pragma unroll
  for (int rt=0;rt<4;rt++){
    #pragma unroll
    for (int ct=0;ct<4;ct++){
      const int col = col0 + ct*16 + lr;
      #pragma unroll
      for (int r=0;r<4;r++){
        const int row = row0 + rt*16 + lq*4 + r;
        out[(size_t)row*DIM + col] = acc[rt][ct][r];
      }
    }
  }
}

extern "C" void kernel_launch(void* const* d_in, const int* in_sizes, int n_in,
                              void* d_out, int out_size, void* d_ws, size_t ws_size,
                              hipStream_t stream){
  const float* x   = (const float*)d_in[0];
  const float* vi  = (const float*)d_in[1];
  const float* Wq  = (const float*)d_in[2];
  const float* Wk  = (const float*)d_in[3];
  const float* Wv  = (const float*)d_in[4];
  const float* Wp  = (const float*)d_in[5];
  const float* lamb= (const float*)d_in[6];

  const size_t XN = (size_t)T_SEQ*DIM;   // 1572864
  const size_t WN = (size_t)DIM*DIM;     // 589824
  char* ws = (char*)d_ws;
  unsigned short* xb    = (unsigned short*)ws; ws += XN*2;
  unsigned short* wqkvb = (unsigned short*)ws; ws += 3*WN*2;
  unsigned short* wpb   = (unsigned short*)ws; ws += WN*2;
  unsigned short* qb    = (unsigned short*)ws; ws += XN*2;
  unsigned short* kb    = (unsigned short*)ws; ws += XN*2;
  unsigned short* vT    = (unsigned short*)ws; ws += XN*2;
  unsigned short* yb    = xb;  // alias: xb dead after qkv_kernel

  convert_kernel<<<1024, 256, 0, stream>>>(x, Wq, Wk, Wv, Wp, xb, wqkvb, wpb);
  qkv_kernel<<<dim3(32,36), 64, 0, stream>>>(xb, wqkvb, vi, lamb, qb, kb, vT);
  attn_kernel<<<dim3(128,12), 512, 0, stream>>>(qb, kb, vT, yb);
  proj_kernel<<<dim3(32,12), 64, 0, stream>>>(yb, wpb, (float*)d_out);
}

// Round 10
// 191.550 us; speedup vs baseline: 1.0942x; 1.0942x over previous
//
#include <hip/hip_runtime.h>

#define T_SEQ 2048
#define DIM   768
#define NH    12
#define HD    64

typedef __attribute__((ext_vector_type(8))) short short8;
typedef __attribute__((ext_vector_type(4))) float floatx4;
typedef __attribute__((ext_vector_type(4))) unsigned short ushort4v;

#define MFMA16(a,b,c) __builtin_amdgcn_mfma_f32_16x16x32_bf16((a),(b),(c),0,0,0)

static __device__ __forceinline__ unsigned short f2bf(float f){
  union { float f; unsigned u; } v; v.f = f;
  unsigned r = v.u + 0x7fffu + ((v.u >> 16) & 1u);
  return (unsigned short)(r >> 16);
}
static __device__ __forceinline__ float bf2f(unsigned short u){
  union { unsigned u; float f; } v; v.u = ((unsigned)u) << 16;
  return v.f;
}

// ---------------- fp32 -> bf16 conversion of x, Wq|Wk|Wv, Wp ----------------
__global__ void convert_kernel(const float* __restrict__ x,
                               const float* __restrict__ wq,
                               const float* __restrict__ wk,
                               const float* __restrict__ wv,
                               const float* __restrict__ wp,
                               unsigned short* __restrict__ xb,
                               unsigned short* __restrict__ wqkvb,
                               unsigned short* __restrict__ wpb){
  const int stride = gridDim.x * blockDim.x;
  const int i0 = blockIdx.x * blockDim.x + threadIdx.x;
  const int XN = T_SEQ * DIM;
  const int WN = DIM * DIM;
  for (int i = i0; i < XN; i += stride) xb[i] = f2bf(x[i]);
  for (int i = i0; i < WN; i += stride) {
    wqkvb[i]        = f2bf(wq[i]);
    wqkvb[WN + i]   = f2bf(wk[i]);
    wqkvb[2*WN + i] = f2bf(wv[i]);
    wpb[i]          = f2bf(wp[i]);
  }
}

// ---------------- QKV projection + lerp + rmsnorm + rope --------------------
// One wave per block computes a 64x64 output tile (4x4 MFMA accumulators).
// grid (32, 36): cb/12 = {q,k,v}, cb%12 = head.
__global__ __launch_bounds__(64) void qkv_kernel(
    const unsigned short* __restrict__ xb,
    const unsigned short* __restrict__ wqkvb,
    const float* __restrict__ vi,
    const float* __restrict__ lambp,
    unsigned short* __restrict__ qb,   // [NH][T][HD]
    unsigned short* __restrict__ kb,   // [NH][T][HD]
    unsigned short* __restrict__ vT){  // [NH][HD][T]
  const int l  = threadIdx.x;
  const int lr = l & 15, lq = l >> 4;
  const int rb = blockIdx.x, cb = blockIdx.y;
  const int mat = cb / NH, head = cb % NH;
  const int row0 = rb*64;

  floatx4 acc[4][4];
  #pragma unroll
  for (int i=0;i<4;i++)
    #pragma unroll
    for (int j=0;j<4;j++) acc[i][j] = (floatx4){0.f,0.f,0.f,0.f};

  const unsigned short* Ab = xb + (size_t)(row0 + lr)*DIM + lq*8;
  const unsigned short* Bb = wqkvb + (size_t)mat*DIM*DIM
                           + (size_t)(head*HD + lr)*DIM + lq*8;

  short8 a[4], b[4];
  #pragma unroll
  for (int rt=0;rt<4;rt++) a[rt] = *(const short8*)(Ab + (size_t)rt*16*DIM);
  #pragma unroll
  for (int ct=0;ct<4;ct++) b[ct] = *(const short8*)(Bb + (size_t)ct*16*DIM);

  for (int k0 = 0; k0 < DIM; k0 += 32){
    const int kn = (k0 + 32 < DIM) ? k0 + 32 : 0;   // wrap tail: unconditional loads
    short8 an[4], bn[4];
    #pragma unroll
    for (int rt=0;rt<4;rt++) an[rt] = *(const short8*)(Ab + (size_t)rt*16*DIM + kn);
    #pragma unroll
    for (int ct=0;ct<4;ct++) bn[ct] = *(const short8*)(Bb + (size_t)ct*16*DIM + kn);
    #pragma unroll
    for (int rt=0;rt<4;rt++)
      #pragma unroll
      for (int ct=0;ct<4;ct++)
        acc[rt][ct] = MFMA16(a[rt], b[ct], acc[rt][ct]);
    #pragma unroll
    for (int rt=0;rt<4;rt++) a[rt] = an[rt];
    #pragma unroll
    for (int ct=0;ct<4;ct++) b[ct] = bn[ct];
  }

  if (mat == 2){
    const float lamb = *lambp;
    #pragma unroll
    for (int rt=0;rt<4;rt++){
      const int tb = row0 + rt*16 + lq*4;
      #pragma unroll
      for (int ct=0;ct<4;ct++){
        const int d = ct*16 + lr;
        ushort4v pk;
        #pragma unroll
        for (int r=0;r<4;r++){
          float vv = (1.0f - lamb)*acc[rt][ct][r]
                   + lamb * vi[(size_t)(tb + r)*DIM + head*HD + d];
          pk[r] = f2bf(vv);
        }
        *(ushort4v*)(vT + (size_t)(head*HD + d)*T_SEQ + tb) = pk;
      }
    }
  } else {
    unsigned short* dst = (mat==0 ? qb : kb) + (size_t)head*T_SEQ*HD;
    #pragma unroll
    for (int rt=0;rt<4;rt++){
      float ss[4];
      #pragma unroll
      for (int r=0;r<4;r++)
        ss[r] = acc[rt][0][r]*acc[rt][0][r] + acc[rt][1][r]*acc[rt][1][r]
              + acc[rt][2][r]*acc[rt][2][r] + acc[rt][3][r]*acc[rt][3][r];
      #pragma unroll
      for (int mm=1; mm<16; mm<<=1){
        #pragma unroll
        for (int r=0;r<4;r++) ss[r] += __shfl_xor(ss[r], mm);
      }
      float scl[4];
      #pragma unroll
      for (int r=0;r<4;r++)
        scl[r] = rsqrtf(ss[r]*(1.0f/64.0f) + 1.1920929e-7f);

      #pragma unroll
      for (int ct=0;ct<2;ct++){
        const int i = ct*16 + lr;               // rope pair index 0..31
        const float inv = __expf(-(float)i * (9.210340371976184f/32.0f));
        #pragma unroll
        for (int r=0;r<4;r++){
          const int t = row0 + rt*16 + lq*4 + r;
          const float f = (float)t * inv;
          const float c = cosf(f), s = sinf(f);
          const float x1 = acc[rt][ct][r]*scl[r], x2 = acc[rt][ct+2][r]*scl[r];
          dst[(size_t)t*HD + i]      = f2bf(x1*c + x2*s);
          dst[(size_t)t*HD + i + 32] = f2bf(x2*c - x1*s);
        }
      }
    }
  }
}

// ---------------- causal flash attention ------------------------------------
// Fixed-max softmax (rmsnorm rows have norm 8 => s in [-8,8], use max=8).
// grid (64, 12), 512 threads = 8 waves. Block bx handles q-tiles (127-bx)
// then bx (pairing => every block equal work, immune to CU/bx aliasing).
// Within a phase the 8 waves split the key range (kt = w, w+8, ...).
// Partials are plain sums (shared fixed max): bf16 O-partials + l via LDS.
__global__ __launch_bounds__(512) void attn_kernel(
    const unsigned short* __restrict__ qb,
    const unsigned short* __restrict__ kb,
    const unsigned short* __restrict__ vT,
    unsigned short* __restrict__ yb){   // [T][DIM] token-major
  __shared__ unsigned short plds[8][16*40];   // per-wave P slab, 10240 B
  __shared__ unsigned short Osh[8][64][20];   // bf16 partials, pad 20, 20480 B
  __shared__ float lsh[8][16];                // 512 B
  const int w  = threadIdx.x >> 6;
  const int l  = threadIdx.x & 63;
  const int lr = l & 15, lq = l >> 4;
  const int head = blockIdx.y;

  const unsigned short* Q = qb + (size_t)head*T_SEQ*HD;
  const unsigned short* K = kb + (size_t)head*T_SEQ*HD;
  const unsigned short* V = vT + (size_t)head*HD*T_SEQ;

  #pragma unroll
  for (int ph = 0; ph < 2; ph++){
    const int qt = ph ? (int)blockIdx.x : (127 - (int)blockIdx.x);  // heavy first
    const int q0 = qt*16;

    const short8 qf0 = *(const short8*)(Q + (size_t)(q0+lr)*HD + lq*8);
    const short8 qf1 = *(const short8*)(Q + (size_t)(q0+lr)*HD + 32 + lq*8);

    floatx4 O[4];
    #pragma unroll
    for (int nt=0; nt<4; nt++) O[nt] = (floatx4){0.f,0.f,0.f,0.f};
    float lsum[4] = {0.f,0.f,0.f,0.f};

    const int ntile = (q0 + 15)/32 + 1;
    int kt = w;
    short8 kf0, kf1, kf2, kf3;
    if (kt < ntile){
      const unsigned short* kp = K + (size_t)(kt*32 + lr)*HD + lq*8;
      kf0 = *(const short8*)kp;            kf1 = *(const short8*)(kp + 32);
      kf2 = *(const short8*)(kp + 16*HD);  kf3 = *(const short8*)(kp + 16*HD + 32);
    }
    for (; kt < ntile; kt += 8){
      const int kbase = kt*32;
      short8 vf[4];
      #pragma unroll
      for (int nt=0; nt<4; nt++)
        vf[nt] = *(const short8*)(V + (size_t)(nt*16 + lr)*T_SEQ + kbase + lq*8);

      floatx4 S0 = (floatx4){0.f,0.f,0.f,0.f};
      floatx4 S1 = (floatx4){0.f,0.f,0.f,0.f};
      S0 = MFMA16(qf0, kf0, S0);
      S0 = MFMA16(qf1, kf1, S0);
      S1 = MFMA16(qf0, kf2, S1);
      S1 = MFMA16(qf1, kf3, S1);

      const int ktn = kt + 8;
      if (ktn < ntile){
        const unsigned short* kp = K + (size_t)(ktn*32 + lr)*HD + lq*8;
        kf0 = *(const short8*)kp;            kf1 = *(const short8*)(kp + 32);
        kf2 = *(const short8*)(kp + 16*HD);  kf3 = *(const short8*)(kp + 16*HD + 32);
      }

      // p = exp(s - 8), s = S*0.125  =>  exp2(S*0.125*log2e - 8*log2e)
      float p0[4], p1[4];
      const int qr = q0 + lq*4;
      #pragma unroll
      for (int r=0; r<4; r++){
        float e0 = __builtin_amdgcn_exp2f(S0[r]*0.18033688011112043f - 11.541560327111707f);
        float e1 = __builtin_amdgcn_exp2f(S1[r]*0.18033688011112043f - 11.541560327111707f);
        p0[r] = (kbase + lr      > qr + r) ? 0.f : e0;
        p1[r] = (kbase + 16 + lr > qr + r) ? 0.f : e1;
        lsum[r] += p0[r] + p1[r];
      }

      // P: C-layout -> A-layout through per-wave LDS slab (single buffer:
      // the lgkmcnt(0) + register consumption orders write -> read -> rewrite)
      unsigned short* pl = &plds[w][0];
      #pragma unroll
      for (int r=0; r<4; r++){
        const int row = lq*4 + r;
        pl[row*40 + lr]      = f2bf(p0[r]);
        pl[row*40 + 16 + lr] = f2bf(p1[r]);
      }
      __asm__ volatile("s_waitcnt lgkmcnt(0)" ::: "memory");
      const short8 pf = *(const short8*)(pl + lr*40 + lq*8);

      #pragma unroll
      for (int nt=0; nt<4; nt++) O[nt] = MFMA16(pf, vf[nt], O[nt]);
    }

    // per-wave l reduction (rows lq*4+r live across the 16 lr lanes)
    #pragma unroll
    for (int mm=1; mm<16; mm<<=1){
      #pragma unroll
      for (int r=0; r<4; r++) lsum[r] += __shfl_xor(lsum[r], mm);
    }

    if (lr == 0){
      #pragma unroll
      for (int r=0; r<4; r++) lsh[w][lq*4+r] = lsum[r];
    }
    #pragma unroll
    for (int nt=0; nt<4; nt++){
      ushort4v pk;
      #pragma unroll
      for (int r=0; r<4; r++) pk[r] = f2bf(O[nt][r]);
      *(ushort4v*)&Osh[w][l][nt*4] = pk;
    }
    __syncthreads();

    // waves 0..3 each merge one 16-col tile (nt = w)
    if (w < 4){
      const int nt = w;
      float L[4] = {0.f,0.f,0.f,0.f};
      float Of[4] = {0.f,0.f,0.f,0.f};
      #pragma unroll
      for (int ww=0; ww<8; ww++){
        #pragma unroll
        for (int r=0; r<4; r++) L[r] += lsh[ww][lq*4+r];
        ushort4v pk = *(const ushort4v*)&Osh[ww][l][nt*4];
        #pragma unroll
        for (int r=0; r<4; r++) Of[r] += bf2f(pk[r]);
      }
      #pragma unroll
      for (int r=0; r<4; r++){
        yb[(size_t)(q0 + lq*4 + r)*DIM + head*HD + nt*16 + lr]
            = f2bf(Of[r] / L[r]);
      }
    }
    __syncthreads();   // protect Osh/lsh before next phase's publish
  }
}

// ---------------- output projection (fp32 out, 64x64 per wave) --------------
// grid (32, 12), one wave per block.
__global__ __launch_bounds__(64) void proj_kernel(
    const unsigned short* __restrict__ yb,
    const unsigned short* __restrict__ wpb,
    float* __restrict__ out){
  const int l  = threadIdx.x;
  const int lr = l & 15, lq = l >> 4;
  const int rb = blockIdx.x, cb = blockIdx.y;
  const int row0 = rb*64, col0 = cb*64;

  floatx4 acc[4][4];
  #pragma unroll
  for (int i=0;i<4;i++)
    #pragma unroll
    for (int j=0;j<4;j++) acc[i][j] = (floatx4){0.f,0.f,0.f,0.f};

  const unsigned short* Ab = yb + (size_t)(row0 + lr)*DIM + lq*8;
  const unsigned short* Bb = wpb + (size_t)(col0 + lr)*DIM + lq*8;

  short8 a[4], b[4];
  #pragma unroll
  for (int rt=0;rt<4;rt++) a[rt] = *(const short8*)(Ab + (size_t)rt*16*DIM);
  #pragma unroll
  for (int ct=0;ct<4;ct++) b[ct] = *(const short8*)(Bb + (size_t)ct*16*DIM);

  for (int k0 = 0; k0 < DIM; k0 += 32){
    const int kn = (k0 + 32 < DIM) ? k0 + 32 : 0;
    short8 an[4], bn[4];
    #pragma unroll
    for (int rt=0;rt<4;rt++) an[rt] = *(const short8*)(Ab + (size_t)rt*16*DIM + kn);
    #pragma unroll
    for (int ct=0;ct<4;ct++) bn[ct] = *(const short8*)(Bb + (size_t)ct*16*DIM + kn);
    #pragma unroll
    for (int rt=0;rt<4;rt++)
      #pragma unroll
      for (int ct=0;ct<4;ct++)
        acc[rt][ct] = MFMA16(a[rt], b[ct], acc[rt][ct]);
    #pragma unroll
    for (int rt=0;rt<4;rt++) a[rt] = an[rt];
    #pragma unroll
    for (int ct=0;ct<4;ct++) b[ct] = bn[ct];
  }

  #pragma unroll
  for (int rt=0;rt<4;rt++){
    #pragma unroll
    for (int ct=0;ct<4;ct++){
      const int col = col0 + ct*16 + lr;
      #pragma unroll
      for (int r=0;r<4;r++){
        const int row = row0 + rt*16 + lq*4 + r;
        out[(size_t)row*DIM + col] = acc[rt][ct][r];
      }
    }
  }
}

extern "C" void kernel_launch(void* const* d_in, const int* in_sizes, int n_in,
                              void* d_out, int out_size, void* d_ws, size_t ws_size,
                              hipStream_t stream){
  const float* x   = (const float*)d_in[0];
  const float* vi  = (const float*)d_in[1];
  const float* Wq  = (const float*)d_in[2];
  const float* Wk  = (const float*)d_in[3];
  const float* Wv  = (const float*)d_in[4];
  const float* Wp  = (const float*)d_in[5];
  const float* lamb= (const float*)d_in[6];

  const size_t XN = (size_t)T_SEQ*DIM;   // 1572864
  const size_t WN = (size_t)DIM*DIM;     // 589824
  char* ws = (char*)d_ws;
  unsigned short* xb    = (unsigned short*)ws; ws += XN*2;
  unsigned short* wqkvb = (unsigned short*)ws; ws += 3*WN*2;
  unsigned short* wpb   = (unsigned short*)ws; ws += WN*2;
  unsigned short* qb    = (unsigned short*)ws; ws += XN*2;
  unsigned short* kb    = (unsigned short*)ws; ws += XN*2;
  unsigned short* vT    = (unsigned short*)ws; ws += XN*2;
  unsigned short* yb    = xb;  // alias: xb dead after qkv_kernel

  convert_kernel<<<1024, 256, 0, stream>>>(x, Wq, Wk, Wv, Wp, xb, wqkvb, wpb);
  qkv_kernel<<<dim3(32,36), 64, 0, stream>>>(xb, wqkvb, vi, lamb, qb, kb, vT);
  attn_kernel<<<dim3(64,12), 512, 0, stream>>>(qb, kb, vT, yb);
  proj_kernel<<<dim3(32,12), 64, 0, stream>>>(yb, wpb, (float*)d_out);
}

// Round 11
// 180.839 us; speedup vs baseline: 1.1590x; 1.0592x over previous
//
#include <hip/hip_runtime.h>

#define T_SEQ 2048
#define DIM   768
#define NH    12
#define HD    64
#define VST   2080   // vT row stride (T_SEQ + 32): breaks 4KB L1-set aliasing

typedef __attribute__((ext_vector_type(8))) short short8;
typedef __attribute__((ext_vector_type(4))) float floatx4;
typedef __attribute__((ext_vector_type(4))) unsigned short ushort4v;

#define MFMA16(a,b,c) __builtin_amdgcn_mfma_f32_16x16x32_bf16((a),(b),(c),0,0,0)

static __device__ __forceinline__ unsigned short f2bf(float f){
  union { float f; unsigned u; } v; v.f = f;
  unsigned r = v.u + 0x7fffu + ((v.u >> 16) & 1u);
  return (unsigned short)(r >> 16);
}
static __device__ __forceinline__ float bf2f(unsigned short u){
  union { unsigned u; float f; } v; v.u = ((unsigned)u) << 16;
  return v.f;
}

// ---------------- fp32 -> bf16 conversion of x, Wq|Wk|Wv, Wp ----------------
__global__ void convert_kernel(const float* __restrict__ x,
                               const float* __restrict__ wq,
                               const float* __restrict__ wk,
                               const float* __restrict__ wv,
                               const float* __restrict__ wp,
                               unsigned short* __restrict__ xb,
                               unsigned short* __restrict__ wqkvb,
                               unsigned short* __restrict__ wpb){
  const int stride = gridDim.x * blockDim.x;
  const int i0 = blockIdx.x * blockDim.x + threadIdx.x;
  const int XN = T_SEQ * DIM;
  const int WN = DIM * DIM;
  for (int i = i0; i < XN; i += stride) xb[i] = f2bf(x[i]);
  for (int i = i0; i < WN; i += stride) {
    wqkvb[i]        = f2bf(wq[i]);
    wqkvb[WN + i]   = f2bf(wk[i]);
    wqkvb[2*WN + i] = f2bf(wv[i]);
    wpb[i]          = f2bf(wp[i]);
  }
}

// ---------------- QKV projection + lerp + rmsnorm + rope --------------------
// One wave per block computes a 64x64 output tile (4x4 MFMA accumulators).
// grid (32, 36): cb/12 = {q,k,v}, cb%12 = head.
__global__ __launch_bounds__(64) void qkv_kernel(
    const unsigned short* __restrict__ xb,
    const unsigned short* __restrict__ wqkvb,
    const float* __restrict__ vi,
    const float* __restrict__ lambp,
    unsigned short* __restrict__ qb,   // [NH][T][HD]
    unsigned short* __restrict__ kb,   // [NH][T][HD]
    unsigned short* __restrict__ vT){  // [NH][HD][VST]
  const int l  = threadIdx.x;
  const int lr = l & 15, lq = l >> 4;
  const int rb = blockIdx.x, cb = blockIdx.y;
  const int mat = cb / NH, head = cb % NH;
  const int row0 = rb*64;

  floatx4 acc[4][4];
  #pragma unroll
  for (int i=0;i<4;i++)
    #pragma unroll
    for (int j=0;j<4;j++) acc[i][j] = (floatx4){0.f,0.f,0.f,0.f};

  const unsigned short* Ab = xb + (size_t)(row0 + lr)*DIM + lq*8;
  const unsigned short* Bb = wqkvb + (size_t)mat*DIM*DIM
                           + (size_t)(head*HD + lr)*DIM + lq*8;

  short8 a[4], b[4];
  #pragma unroll
  for (int rt=0;rt<4;rt++) a[rt] = *(const short8*)(Ab + (size_t)rt*16*DIM);
  #pragma unroll
  for (int ct=0;ct<4;ct++) b[ct] = *(const short8*)(Bb + (size_t)ct*16*DIM);

  for (int k0 = 0; k0 < DIM; k0 += 32){
    const int kn = (k0 + 32 < DIM) ? k0 + 32 : 0;   // wrap tail: unconditional loads
    short8 an[4], bn[4];
    #pragma unroll
    for (int rt=0;rt<4;rt++) an[rt] = *(const short8*)(Ab + (size_t)rt*16*DIM + kn);
    #pragma unroll
    for (int ct=0;ct<4;ct++) bn[ct] = *(const short8*)(Bb + (size_t)ct*16*DIM + kn);
    #pragma unroll
    for (int rt=0;rt<4;rt++)
      #pragma unroll
      for (int ct=0;ct<4;ct++)
        acc[rt][ct] = MFMA16(a[rt], b[ct], acc[rt][ct]);
    #pragma unroll
    for (int rt=0;rt<4;rt++) a[rt] = an[rt];
    #pragma unroll
    for (int ct=0;ct<4;ct++) b[ct] = bn[ct];
  }

  if (mat == 2){
    const float lamb = *lambp;
    #pragma unroll
    for (int rt=0;rt<4;rt++){
      const int tb = row0 + rt*16 + lq*4;
      #pragma unroll
      for (int ct=0;ct<4;ct++){
        const int d = ct*16 + lr;
        ushort4v pk;
        #pragma unroll
        for (int r=0;r<4;r++){
          float vv = (1.0f - lamb)*acc[rt][ct][r]
                   + lamb * vi[(size_t)(tb + r)*DIM + head*HD + d];
          pk[r] = f2bf(vv);
        }
        *(ushort4v*)(vT + (size_t)(head*HD + d)*VST + tb) = pk;
      }
    }
  } else {
    unsigned short* dst = (mat==0 ? qb : kb) + (size_t)head*T_SEQ*HD;
    #pragma unroll
    for (int rt=0;rt<4;rt++){
      float ss[4];
      #pragma unroll
      for (int r=0;r<4;r++)
        ss[r] = acc[rt][0][r]*acc[rt][0][r] + acc[rt][1][r]*acc[rt][1][r]
              + acc[rt][2][r]*acc[rt][2][r] + acc[rt][3][r]*acc[rt][3][r];
      #pragma unroll
      for (int mm=1; mm<16; mm<<=1){
        #pragma unroll
        for (int r=0;r<4;r++) ss[r] += __shfl_xor(ss[r], mm);
      }
      float scl[4];
      #pragma unroll
      for (int r=0;r<4;r++)
        scl[r] = rsqrtf(ss[r]*(1.0f/64.0f) + 1.1920929e-7f);

      #pragma unroll
      for (int ct=0;ct<2;ct++){
        const int i = ct*16 + lr;               // rope pair index 0..31
        const float inv = __expf(-(float)i * (9.210340371976184f/32.0f));
        #pragma unroll
        for (int r=0;r<4;r++){
          const int t = row0 + rt*16 + lq*4 + r;
          const float f = (float)t * inv;
          const float c = cosf(f), s = sinf(f);
          const float x1 = acc[rt][ct][r]*scl[r], x2 = acc[rt][ct+2][r]*scl[r];
          dst[(size_t)t*HD + i]      = f2bf(x1*c + x2*s);
          dst[(size_t)t*HD + i + 32] = f2bf(x2*c - x1*s);
        }
      }
    }
  }
}

// ---------------- causal flash attention ------------------------------------
// Fixed-max softmax (rmsnorm rows have norm 8 => s in [-8,8], use max=8).
// grid (64, 12), 512 threads = 8 waves. Block bx handles q-tiles (127-bx)
// then bx (pairing => every block equal work, immune to CU/bx aliasing).
// V is read from the padded vT (stride VST) so each 16-lane gather spans
// 16 distinct L1 sets instead of one.
__global__ __launch_bounds__(512) void attn_kernel(
    const unsigned short* __restrict__ qb,
    const unsigned short* __restrict__ kb,
    const unsigned short* __restrict__ vT,
    unsigned short* __restrict__ yb){   // [T][DIM] token-major
  __shared__ unsigned short plds[8][16*40];   // per-wave P slab, 10240 B
  __shared__ unsigned short Osh[8][64][20];   // bf16 partials, pad 20, 20480 B
  __shared__ float lsh[8][16];                // 512 B
  const int w  = threadIdx.x >> 6;
  const int l  = threadIdx.x & 63;
  const int lr = l & 15, lq = l >> 4;
  const int head = blockIdx.y;

  const unsigned short* Q = qb + (size_t)head*T_SEQ*HD;
  const unsigned short* K = kb + (size_t)head*T_SEQ*HD;
  const unsigned short* V = vT + (size_t)head*HD*VST;

  #pragma unroll
  for (int ph = 0; ph < 2; ph++){
    const int qt = ph ? (int)blockIdx.x : (127 - (int)blockIdx.x);  // heavy first
    const int q0 = qt*16;

    const short8 qf0 = *(const short8*)(Q + (size_t)(q0+lr)*HD + lq*8);
    const short8 qf1 = *(const short8*)(Q + (size_t)(q0+lr)*HD + 32 + lq*8);

    floatx4 O[4];
    #pragma unroll
    for (int nt=0; nt<4; nt++) O[nt] = (floatx4){0.f,0.f,0.f,0.f};
    float lsum[4] = {0.f,0.f,0.f,0.f};

    const int ntile = (q0 + 15)/32 + 1;
    int kt = w;
    short8 kf0, kf1, kf2, kf3;
    if (kt < ntile){
      const unsigned short* kp = K + (size_t)(kt*32 + lr)*HD + lq*8;
      kf0 = *(const short8*)kp;            kf1 = *(const short8*)(kp + 32);
      kf2 = *(const short8*)(kp + 16*HD);  kf3 = *(const short8*)(kp + 16*HD + 32);
    }
    for (; kt < ntile; kt += 8){
      const int kbase = kt*32;
      short8 vf[4];
      #pragma unroll
      for (int nt=0; nt<4; nt++)
        vf[nt] = *(const short8*)(V + (size_t)(nt*16 + lr)*VST + kbase + lq*8);

      floatx4 S0 = (floatx4){0.f,0.f,0.f,0.f};
      floatx4 S1 = (floatx4){0.f,0.f,0.f,0.f};
      S0 = MFMA16(qf0, kf0, S0);
      S0 = MFMA16(qf1, kf1, S0);
      S1 = MFMA16(qf0, kf2, S1);
      S1 = MFMA16(qf1, kf3, S1);

      const int ktn = kt + 8;
      if (ktn < ntile){
        const unsigned short* kp = K + (size_t)(ktn*32 + lr)*HD + lq*8;
        kf0 = *(const short8*)kp;            kf1 = *(const short8*)(kp + 32);
        kf2 = *(const short8*)(kp + 16*HD);  kf3 = *(const short8*)(kp + 16*HD + 32);
      }

      // p = exp(s - 8), s = S*0.125  =>  exp2(S*0.125*log2e - 8*log2e)
      float p0[4], p1[4];
      const int qr = q0 + lq*4;
      #pragma unroll
      for (int r=0; r<4; r++){
        float e0 = __builtin_amdgcn_exp2f(S0[r]*0.18033688011112043f - 11.541560327111707f);
        float e1 = __builtin_amdgcn_exp2f(S1[r]*0.18033688011112043f - 11.541560327111707f);
        p0[r] = (kbase + lr      > qr + r) ? 0.f : e0;
        p1[r] = (kbase + 16 + lr > qr + r) ? 0.f : e1;
        lsum[r] += p0[r] + p1[r];
      }

      // P: C-layout -> A-layout through per-wave LDS slab
      unsigned short* pl = &plds[w][0];
      #pragma unroll
      for (int r=0; r<4; r++){
        const int row = lq*4 + r;
        pl[row*40 + lr]      = f2bf(p0[r]);
        pl[row*40 + 16 + lr] = f2bf(p1[r]);
      }
      __asm__ volatile("s_waitcnt lgkmcnt(0)" ::: "memory");
      const short8 pf = *(const short8*)(pl + lr*40 + lq*8);

      #pragma unroll
      for (int nt=0; nt<4; nt++) O[nt] = MFMA16(pf, vf[nt], O[nt]);
    }

    // per-wave l reduction (rows lq*4+r live across the 16 lr lanes)
    #pragma unroll
    for (int mm=1; mm<16; mm<<=1){
      #pragma unroll
      for (int r=0; r<4; r++) lsum[r] += __shfl_xor(lsum[r], mm);
    }

    if (lr == 0){
      #pragma unroll
      for (int r=0; r<4; r++) lsh[w][lq*4+r] = lsum[r];
    }
    #pragma unroll
    for (int nt=0; nt<4; nt++){
      ushort4v pk;
      #pragma unroll
      for (int r=0; r<4; r++) pk[r] = f2bf(O[nt][r]);
      *(ushort4v*)&Osh[w][l][nt*4] = pk;
    }
    __syncthreads();

    // waves 0..3 each merge one 16-col tile (nt = w)
    if (w < 4){
      const int nt = w;
      float L[4] = {0.f,0.f,0.f,0.f};
      float Of[4] = {0.f,0.f,0.f,0.f};
      #pragma unroll
      for (int ww=0; ww<8; ww++){
        #pragma unroll
        for (int r=0; r<4; r++) L[r] += lsh[ww][lq*4+r];
        ushort4v pk = *(const ushort4v*)&Osh[ww][l][nt*4];
        #pragma unroll
        for (int r=0; r<4; r++) Of[r] += bf2f(pk[r]);
      }
      #pragma unroll
      for (int r=0; r<4; r++){
        yb[(size_t)(q0 + lq*4 + r)*DIM + head*HD + nt*16 + lr]
            = f2bf(Of[r] / L[r]);
      }
    }
    __syncthreads();   // protect Osh/lsh before next phase's publish
  }
}

// ---------------- output projection (fp32 out, 64x64 per wave) --------------
// grid (32, 12), one wave per block.
__global__ __launch_bounds__(64) void proj_kernel(
    const unsigned short* __restrict__ yb,
    const unsigned short* __restrict__ wpb,
    float* __restrict__ out){
  const int l  = threadIdx.x;
  const int lr = l & 15, lq = l >> 4;
  const int rb = blockIdx.x, cb = blockIdx.y;
  const int row0 = rb*64, col0 = cb*64;

  floatx4 acc[4][4];
  #pragma unroll
  for (int i=0;i<4;i++)
    #pragma unroll
    for (int j=0;j<4;j++) acc[i][j] = (floatx4){0.f,0.f,0.f,0.f};

  const unsigned short* Ab = yb + (size_t)(row0 + lr)*DIM + lq*8;
  const unsigned short* Bb = wpb + (size_t)(col0 + lr)*DIM + lq*8;

  short8 a[4], b[4];
  #pragma unroll
  for (int rt=0;rt<4;rt++) a[rt] = *(const short8*)(Ab + (size_t)rt*16*DIM);
  #pragma unroll
  for (int ct=0;ct<4;ct++) b[ct] = *(const short8*)(Bb + (size_t)ct*16*DIM);

  for (int k0 = 0; k0 < DIM; k0 += 32){
    const int kn = (k0 + 32 < DIM) ? k0 + 32 : 0;
    short8 an[4], bn[4];
    #pragma unroll
    for (int rt=0;rt<4;rt++) an[rt] = *(const short8*)(Ab + (size_t)rt*16*DIM + kn);
    #pragma unroll
    for (int ct=0;ct<4;ct++) bn[ct] = *(const short8*)(Bb + (size_t)ct*16*DIM + kn);
    #pragma unroll
    for (int rt=0;rt<4;rt++)
      #pragma unroll
      for (int ct=0;ct<4;ct++)
        acc[rt][ct] = MFMA16(a[rt], b[ct], acc[rt][ct]);
    #pragma unroll
    for (int rt=0;rt<4;rt++) a[rt] = an[rt];
    #pragma unroll
    for (int ct=0;ct<4;ct++) b[ct] = bn[ct];
  }

  #pragma unroll
  for (int rt=0;rt<4;rt++){
    #pragma unroll
    for (int ct=0;ct<4;ct++){
      const int col = col0 + ct*16 + lr;
      #pragma unroll
      for (int r=0;r<4;r++){
        const int row = row0 + rt*16 + lq*4 + r;
        out[(size_t)row*DIM + col] = acc[rt][ct][r];
      }
    }
  }
}

extern "C" void kernel_launch(void* const* d_in, const int* in_sizes, int n_in,
                              void* d_out, int out_size, void* d_ws, size_t ws_size,
                              hipStream_t stream){
  const float* x   = (const float*)d_in[0];
  const float* vi  = (const float*)d_in[1];
  const float* Wq  = (const float*)d_in[2];
  const float* Wk  = (const float*)d_in[3];
  const float* Wv  = (const float*)d_in[4];
  const float* Wp  = (const float*)d_in[5];
  const float* lamb= (const float*)d_in[6];

  const size_t XN = (size_t)T_SEQ*DIM;   // 1572864
  const size_t WN = (size_t)DIM*DIM;     // 589824
  const size_t VN = (size_t)NH*HD*VST;   // padded vT
  char* ws = (char*)d_ws;
  unsigned short* xb    = (unsigned short*)ws; ws += XN*2;
  unsigned short* wqkvb = (unsigned short*)ws; ws += 3*WN*2;
  unsigned short* wpb   = (unsigned short*)ws; ws += WN*2;
  unsigned short* qb    = (unsigned short*)ws; ws += XN*2;
  unsigned short* kb    = (unsigned short*)ws; ws += XN*2;
  unsigned short* vT    = (unsigned short*)ws; ws += VN*2;
  unsigned short* yb    = xb;  // alias: xb dead after qkv_kernel

  convert_kernel<<<1024, 256, 0, stream>>>(x, Wq, Wk, Wv, Wp, xb, wqkvb, wpb);
  qkv_kernel<<<dim3(32,36), 64, 0, stream>>>(xb, wqkvb, vi, lamb, qb, kb, vT);
  attn_kernel<<<dim3(64,12), 512, 0, stream>>>(qb, kb, vT, yb);
  proj_kernel<<<dim3(32,12), 64, 0, stream>>>(yb, wpb, (float*)d_out);
}